// Round 1
// baseline (173.427 us; speedup 1.0000x reference)
//
#include <hip/hip_runtime.h>
#include <hip/hip_bf16.h>
#include <stdint.h>
#include <stddef.h>

// Problem: DistanceNetwork — sims[n,b] = dot(support[n], input[b]) * smag[n] * imag
//   support_set: [8192, 1024] fp32   input_image: [2048, 1024] fp32
//   out: [8192, 2048] fp32
#define M_DIM 8192
#define N_DIM 2048
#define K_DIM 1024

#define BM 128
#define BN 128
#define BK 32

typedef __attribute__((ext_vector_type(8))) short short8;   // 8 bf16 = 4 VGPRs
typedef __attribute__((ext_vector_type(4))) float float4v;  // MFMA C/D

// fp32 -> bf16 round-to-nearest-even (inputs are finite normals; no NaN path needed)
static __device__ __forceinline__ unsigned short f2bf(float x) {
  union { float f; unsigned u; } c; c.f = x;
  return (unsigned short)((c.u + 0x7FFFu + ((c.u >> 16) & 1u)) >> 16);
}

#define GLOAD_LDS16(g, l)                                           \
  __builtin_amdgcn_global_load_lds(                                 \
      (const __attribute__((address_space(1))) void*)(g),           \
      (__attribute__((address_space(3))) void*)(l), 16, 0, 0)

// ---------------- prep kernels ----------------

// One block per support row: convert row to bf16 + write rsqrt(row sum-sq).
__global__ __launch_bounds__(256) void support_prep(
    const float* __restrict__ S, unsigned short* __restrict__ Sb,
    float* __restrict__ smag) {
  const int row = blockIdx.x;
  const int t = threadIdx.x;
  const float4 v = reinterpret_cast<const float4*>(S + (size_t)row * K_DIM)[t];
  ushort4 b;
  b.x = f2bf(v.x); b.y = f2bf(v.y); b.z = f2bf(v.z); b.w = f2bf(v.w);
  reinterpret_cast<ushort4*>(Sb + (size_t)row * K_DIM)[t] = b;

  float ss = v.x * v.x + v.y * v.y + v.z * v.z + v.w * v.w;
#pragma unroll
  for (int m = 32; m >= 1; m >>= 1) ss += __shfl_xor(ss, m, 64);
  __shared__ float wsum[4];
  if ((t & 63) == 0) wsum[t >> 6] = ss;
  __syncthreads();
  if (t == 0) {
    float tot = wsum[0] + wsum[1] + wsum[2] + wsum[3];
    smag[row] = rsqrtf(fmaxf(tot, 1e-10f));
  }
}

// Grid-stride convert of input + global sum of squares (atomicAdd per block).
__global__ __launch_bounds__(256) void input_prep(
    const float* __restrict__ I, unsigned short* __restrict__ Ib,
    float* __restrict__ sumsq) {
  const int idx = blockIdx.x * 256 + threadIdx.x;
  const float4 v = reinterpret_cast<const float4*>(I)[idx];
  ushort4 b;
  b.x = f2bf(v.x); b.y = f2bf(v.y); b.z = f2bf(v.z); b.w = f2bf(v.w);
  reinterpret_cast<ushort4*>(Ib)[idx] = b;

  float ss = v.x * v.x + v.y * v.y + v.z * v.z + v.w * v.w;
#pragma unroll
  for (int m = 32; m >= 1; m >>= 1) ss += __shfl_xor(ss, m, 64);
  __shared__ float wsum[4];
  const int t = threadIdx.x;
  if ((t & 63) == 0) wsum[t >> 6] = ss;
  __syncthreads();
  if (t == 0) atomicAdd(sumsq, wsum[0] + wsum[1] + wsum[2] + wsum[3]);
}

// ---------------- GEMM (m97 structure: 128x128 tile, global_load_lds w=16) ----------------
// C[m,n] = sum_k A[m,k]*B[n,k]  (both row-major, K contiguous — NT)
__global__ __launch_bounds__(256) void gemm_bt(
    const unsigned short* __restrict__ A,  // [M, K] bf16 (support)
    const unsigned short* __restrict__ B,  // [N, K] bf16 (input)
    const float* __restrict__ smag,        // [M]
    const float* __restrict__ sumsq,       // [1]
    float* __restrict__ C) {               // [M, N]
  __shared__ unsigned short lA[BM * BK];   // 8 KB, row-major [128][32], NO padding
  __shared__ unsigned short lB[BN * BK];   // (global_load_lds needs contiguous layout)

  const int t = threadIdx.x;
  const int lane = t & 63;
  const int wave = t >> 6;
  const int wr = wave >> 1;  // wave row 0..1 (64 rows each)
  const int wc = wave & 1;   // wave col 0..1

  const int bm = blockIdx.y * BM;
  const int bn = blockIdx.x * BN;

  // Staging: tile = 512 x 16B chunks; chunk c -> row c>>2, k-chunk c&3.
  // Wave w, issue i covers chunks [i*256 + w*64 + lane].
  const int c0 = wave * 64 + lane;
  const int c1 = c0 + 256;
  const unsigned short* gA0 = A + (size_t)(bm + (c0 >> 2)) * K_DIM + (c0 & 3) * 8;
  const unsigned short* gA1 = A + (size_t)(bm + (c1 >> 2)) * K_DIM + (c1 & 3) * 8;
  const unsigned short* gB0 = B + (size_t)(bn + (c0 >> 2)) * K_DIM + (c0 & 3) * 8;
  const unsigned short* gB1 = B + (size_t)(bn + (c1 >> 2)) * K_DIM + (c1 & 3) * 8;
  // wave-uniform LDS bases (HW adds lane*16B)
  unsigned short* lA0 = lA + (size_t)(wave * 64) * 8;
  unsigned short* lA1 = lA + (size_t)(256 + wave * 64) * 8;
  unsigned short* lB0 = lB + (size_t)(wave * 64) * 8;
  unsigned short* lB1 = lB + (size_t)(256 + wave * 64) * 8;

  // fragment read bases: A[m=lane&15][k=(lane>>4)*8 + j]
  const int fr = lane & 15;
  const int q = lane >> 4;
  const unsigned short* rA = lA + (wr * 64 + fr) * BK + q * 8;
  const unsigned short* rB = lB + (wc * 64 + fr) * BK + q * 8;

  float4v acc[4][4];
#pragma unroll
  for (int i = 0; i < 4; ++i)
#pragma unroll
    for (int j = 0; j < 4; ++j) acc[i][j] = (float4v)0.0f;

  for (int kt = 0; kt < K_DIM / BK; ++kt) {
    GLOAD_LDS16(gA0, lA0);
    GLOAD_LDS16(gA1, lA1);
    GLOAD_LDS16(gB0, lB0);
    GLOAD_LDS16(gB1, lB1);
    gA0 += BK; gA1 += BK; gB0 += BK; gB1 += BK;
    __syncthreads();  // drains vmcnt(0): LDS filled before reads

    short8 af[4], bf[4];
#pragma unroll
    for (int i = 0; i < 4; ++i)
      af[i] = *reinterpret_cast<const short8*>(rA + i * 16 * BK);
#pragma unroll
    for (int j = 0; j < 4; ++j)
      bf[j] = *reinterpret_cast<const short8*>(rB + j * 16 * BK);
#pragma unroll
    for (int i = 0; i < 4; ++i)
#pragma unroll
      for (int j = 0; j < 4; ++j)
        acc[i][j] = __builtin_amdgcn_mfma_f32_16x16x32_bf16(af[i], bf[j], acc[i][j], 0, 0, 0);

    __syncthreads();  // LDS consumed before next iter overwrites
  }

  // Epilogue: C/D layout col = lane&15, row = (lane>>4)*4 + reg
  const float imag = rsqrtf(fmaxf(*sumsq, 1e-10f));
#pragma unroll
  for (int i = 0; i < 4; ++i) {
    const int rbase = bm + wr * 64 + i * 16 + q * 4;
#pragma unroll
    for (int r = 0; r < 4; ++r) {
      const int row = rbase + r;
      const float s = smag[row] * imag;
      float* crow = C + (size_t)row * N_DIM + bn + wc * 64 + fr;
#pragma unroll
      for (int j = 0; j < 4; ++j) crow[j * 16] = acc[i][j][r] * s;
    }
  }
}

// ---------------- launch ----------------
extern "C" void kernel_launch(void* const* d_in, const int* in_sizes, int n_in,
                              void* d_out, int out_size, void* d_ws, size_t ws_size,
                              hipStream_t stream) {
  const float* S = (const float*)d_in[0];  // support_set [8192,1024]
  const float* I = (const float*)d_in[1];  // input_image [2048,1024]
  float* out = (float*)d_out;

  // ws layout: Sb bf16 (16 MB) | Ib bf16 (4 MB) | smag (32 KB) | sumsq (4 B)
  unsigned char* ws = (unsigned char*)d_ws;
  unsigned short* Sb = (unsigned short*)ws;
  unsigned short* Ib = (unsigned short*)(ws + (size_t)M_DIM * K_DIM * 2);
  float* smag = (float*)(ws + (size_t)M_DIM * K_DIM * 2 + (size_t)N_DIM * K_DIM * 2);
  float* sumsq = (float*)((unsigned char*)smag + (size_t)M_DIM * 4);

  hipMemsetAsync(sumsq, 0, sizeof(float), stream);
  hipLaunchKernelGGL(input_prep, dim3((N_DIM * K_DIM) / (256 * 4)), dim3(256), 0, stream,
                     I, Ib, sumsq);
  hipLaunchKernelGGL(support_prep, dim3(M_DIM), dim3(256), 0, stream, S, Sb, smag);
  hipLaunchKernelGGL(gemm_bt, dim3(N_DIM / BN, M_DIM / BM), dim3(256), 0, stream,
                     Sb, Ib, smag, sumsq, out);
}

// Round 2
// 142.395 us; speedup vs baseline: 1.2179x; 1.2179x over previous
//
#include <hip/hip_runtime.h>
#include <hip/hip_bf16.h>
#include <stdint.h>
#include <stddef.h>

// DistanceNetwork: sims[n,b] = dot(support[n], input[b]) * rsqrt(||support[n]||^2) * rsqrt(||input||_F^2)
//   support_set: [8192, 1024] fp32   input_image: [2048, 1024] fp32   out: [8192, 2048] fp32
#define M_DIM 8192
#define N_DIM 2048
#define K_DIM 1024

#define BM 128
#define BN 128
#define BK 64

typedef __attribute__((ext_vector_type(8))) short short8;   // 8 bf16 = 4 VGPRs
typedef __attribute__((ext_vector_type(4))) float float4v;  // MFMA C/D

// fp32 -> bf16 RNE
static __device__ __forceinline__ unsigned short f2bf(float x) {
  union { float f; unsigned u; } c; c.f = x;
  return (unsigned short)((c.u + 0x7FFFu + ((c.u >> 16) & 1u)) >> 16);
}

#define GLOAD_LDS16(g, l)                                           \
  __builtin_amdgcn_global_load_lds(                                 \
      (const __attribute__((address_space(1))) void*)(g),           \
      (__attribute__((address_space(3))) void*)(l), 16, 0, 0)

// ---------------- prep kernels ----------------

// One block per support row: convert row to bf16 + rsqrt(row sum-sq).
__global__ __launch_bounds__(256) void support_prep(
    const float* __restrict__ S, unsigned short* __restrict__ Sb,
    float* __restrict__ smag) {
  const int row = blockIdx.x;
  const int t = threadIdx.x;
  const float4 v = reinterpret_cast<const float4*>(S + (size_t)row * K_DIM)[t];
  ushort4 b;
  b.x = f2bf(v.x); b.y = f2bf(v.y); b.z = f2bf(v.z); b.w = f2bf(v.w);
  reinterpret_cast<ushort4*>(Sb + (size_t)row * K_DIM)[t] = b;

  float ss = v.x * v.x + v.y * v.y + v.z * v.z + v.w * v.w;
#pragma unroll
  for (int m = 32; m >= 1; m >>= 1) ss += __shfl_xor(ss, m, 64);
  __shared__ float wsum[4];
  if ((t & 63) == 0) wsum[t >> 6] = ss;
  __syncthreads();
  if (t == 0) smag[row] = rsqrtf(fmaxf(wsum[0] + wsum[1] + wsum[2] + wsum[3], 1e-10f));
}

// Convert input + per-block partial sum-of-squares (NO atomics — they serialize
// ~2048 same-address adds at the L2 home bank, ~60 us).
__global__ __launch_bounds__(256) void input_prep(
    const float* __restrict__ I, unsigned short* __restrict__ Ib,
    float* __restrict__ partials) {
  const int idx = blockIdx.x * 256 + threadIdx.x;
  const float4 v = reinterpret_cast<const float4*>(I)[idx];
  ushort4 b;
  b.x = f2bf(v.x); b.y = f2bf(v.y); b.z = f2bf(v.z); b.w = f2bf(v.w);
  reinterpret_cast<ushort4*>(Ib)[idx] = b;

  float ss = v.x * v.x + v.y * v.y + v.z * v.z + v.w * v.w;
#pragma unroll
  for (int m = 32; m >= 1; m >>= 1) ss += __shfl_xor(ss, m, 64);
  __shared__ float wsum[4];
  const int t = threadIdx.x;
  if ((t & 63) == 0) wsum[t >> 6] = ss;
  __syncthreads();
  if (t == 0) partials[blockIdx.x] = wsum[0] + wsum[1] + wsum[2] + wsum[3];
}

// 1 block: reduce 2048 partials -> imag, then scale[m] = smag[m]*imag.
__global__ __launch_bounds__(256) void finalize(
    const float* __restrict__ partials, const float* __restrict__ smag,
    float* __restrict__ scale) {
  const int t = threadIdx.x;
  float s = 0.f;
#pragma unroll
  for (int i = 0; i < 2048 / 256; ++i) s += partials[t + i * 256];
#pragma unroll
  for (int m = 32; m >= 1; m >>= 1) s += __shfl_xor(s, m, 64);
  __shared__ float wsum[4];
  if ((t & 63) == 0) wsum[t >> 6] = s;
  __syncthreads();
  const float imag = rsqrtf(fmaxf(wsum[0] + wsum[1] + wsum[2] + wsum[3], 1e-10f));
  for (int i = t; i < M_DIM; i += 256) scale[i] = smag[i] * imag;
}

// ---------------- GEMM ----------------
// C[m,n] = scale[m] * sum_k A[m,k]*B[n,k]  (both row-major NT), 128x128 tile, BK=64.
// LDS layout XOR-swizzled: global 16B-chunk (row, kc) lives at position
// row*8 + (kc ^ (row&7)) so the ds_read_b128 fragment reads hit the dense
// 8-access/bank floor (row stride = 128 B = full bank wrap otherwise).
__global__ __launch_bounds__(256) void gemm_bt(
    const unsigned short* __restrict__ A,  // [M, K] bf16 (support)
    const unsigned short* __restrict__ B,  // [N, K] bf16 (input)
    const float* __restrict__ scale,       // [M] = smag*imag
    float* __restrict__ C) {               // [M, N]
  __shared__ unsigned short lA[BM * BK];   // 16 KB
  __shared__ unsigned short lB[BN * BK];   // 16 KB

  const int t = threadIdx.x;
  const int lane = t & 63;
  const int wave = t >> 6;
  const int wr = wave >> 1;  // wave row 0..1
  const int wc = wave & 1;   // wave col 0..1

  const int bm = blockIdx.y * BM;
  const int bn = blockIdx.x * BN;

  // Staging: tile = 1024 chunks of 16B. Wave w issue i covers positions
  // p = i*256 + w*64 + lane. Position p holds global (row=p>>3, kc=(p&7)^((p>>3)&7));
  // with p's base a multiple of 64 this reduces to lane-only terms:
  const int rsub = lane >> 3;                       // row sub-index 0..7
  const int kcg = (lane & 7) ^ (rsub & 7);          // swizzled global k-chunk
  const unsigned short* gA[4];
  const unsigned short* gB[4];
  unsigned short* dA[4];
  unsigned short* dB[4];
#pragma unroll
  for (int i = 0; i < 4; ++i) {
    const int row = i * 32 + wave * 8 + rsub;
    gA[i] = A + (size_t)(bm + row) * K_DIM + kcg * 8;
    gB[i] = B + (size_t)(bn + row) * K_DIM + kcg * 8;
    dA[i] = lA + (size_t)(i * 256 + wave * 64) * 8;  // wave-uniform base
    dB[i] = lB + (size_t)(i * 256 + wave * 64) * 8;
  }

  // Fragment read bases: A[m = lane&15][k = (lane>>4)*8 + j]
  const int fr = lane & 15;
  const int q = lane >> 4;
  const unsigned short* rA = lA + (wr * 64 + fr) * BK;
  const unsigned short* rB = lB + (wc * 64 + fr) * BK;
  const int sw = fr & 7;  // read-side swizzle term

  float4v acc[4][4];
#pragma unroll
  for (int i = 0; i < 4; ++i)
#pragma unroll
    for (int j = 0; j < 4; ++j) acc[i][j] = (float4v)0.0f;

  for (int kt = 0; kt < K_DIM / BK; ++kt) {
#pragma unroll
    for (int i = 0; i < 4; ++i) GLOAD_LDS16(gA[i], dA[i]);
#pragma unroll
    for (int i = 0; i < 4; ++i) GLOAD_LDS16(gB[i], dB[i]);
#pragma unroll
    for (int i = 0; i < 4; ++i) { gA[i] += BK; gB[i] += BK; }
    __syncthreads();  // drains vmcnt(0): LDS filled before reads

#pragma unroll
    for (int s = 0; s < 2; ++s) {  // two MFMA k-steps per staged slab
      const int pc = ((4 * s + q) ^ sw) * 8;
      short8 af[4], bfr[4];
#pragma unroll
      for (int i = 0; i < 4; ++i)
        af[i] = *reinterpret_cast<const short8*>(rA + i * 16 * BK + pc);
#pragma unroll
      for (int j = 0; j < 4; ++j)
        bfr[j] = *reinterpret_cast<const short8*>(rB + j * 16 * BK + pc);
#pragma unroll
      for (int i = 0; i < 4; ++i)
#pragma unroll
        for (int j = 0; j < 4; ++j)
          acc[i][j] = __builtin_amdgcn_mfma_f32_16x16x32_bf16(af[i], bfr[j], acc[i][j], 0, 0, 0);
    }
    __syncthreads();  // LDS consumed before next iter overwrites
  }

  // Epilogue: C/D layout col = lane&15, row = (lane>>4)*4 + reg
#pragma unroll
  for (int i = 0; i < 4; ++i) {
    const int rbase = bm + wr * 64 + i * 16 + q * 4;
#pragma unroll
    for (int r = 0; r < 4; ++r) {
      const int row = rbase + r;
      const float s = scale[row];
      float* crow = C + (size_t)row * N_DIM + bn + wc * 64 + fr;
#pragma unroll
      for (int j = 0; j < 4; ++j) crow[j * 16] = acc[i][j][r] * s;
    }
  }
}

// ---------------- launch ----------------
extern "C" void kernel_launch(void* const* d_in, const int* in_sizes, int n_in,
                              void* d_out, int out_size, void* d_ws, size_t ws_size,
                              hipStream_t stream) {
  const float* S = (const float*)d_in[0];  // support_set [8192,1024]
  const float* I = (const float*)d_in[1];  // input_image [2048,1024]
  float* out = (float*)d_out;

  // ws layout: Sb bf16 16MB | Ib bf16 4MB | smag 32KB | partials 8KB | scale 32KB
  unsigned char* ws = (unsigned char*)d_ws;
  unsigned short* Sb = (unsigned short*)ws;
  unsigned short* Ib = (unsigned short*)(ws + (size_t)M_DIM * K_DIM * 2);
  float* smag = (float*)(ws + (size_t)M_DIM * K_DIM * 2 + (size_t)N_DIM * K_DIM * 2);
  float* partials = smag + M_DIM;
  float* scale = partials + 2048;

  hipLaunchKernelGGL(input_prep, dim3((N_DIM * K_DIM) / (256 * 4)), dim3(256), 0, stream,
                     I, Ib, partials);
  hipLaunchKernelGGL(support_prep, dim3(M_DIM), dim3(256), 0, stream, S, Sb, smag);
  hipLaunchKernelGGL(finalize, dim3(1), dim3(256), 0, stream, partials, smag, scale);
  hipLaunchKernelGGL(gemm_bt, dim3(N_DIM / BN, M_DIM / BM), dim3(256), 0, stream,
                     Sb, Ib, scale, out);
}

// Round 3
// 134.657 us; speedup vs baseline: 1.2879x; 1.0575x over previous
//
#include <hip/hip_runtime.h>
#include <hip/hip_bf16.h>
#include <stdint.h>
#include <stddef.h>

// DistanceNetwork: sims[n,b] = dot(support[n], input[b]) * rsqrt(||support[n]||^2) * rsqrt(||input||_F^2)
//   support_set: [8192, 1024] fp32   input_image: [2048, 1024] fp32   out: [8192, 2048] fp32
#define M_DIM 8192
#define N_DIM 2048
#define K_DIM 1024

#define BM 128
#define BN 128
#define BK 64

typedef __attribute__((ext_vector_type(8))) short short8;   // 8 bf16 = 4 VGPRs
typedef __attribute__((ext_vector_type(4))) float float4v;  // MFMA C/D

// fp32 -> bf16 RNE
static __device__ __forceinline__ unsigned short f2bf(float x) {
  union { float f; unsigned u; } c; c.f = x;
  return (unsigned short)((c.u + 0x7FFFu + ((c.u >> 16) & 1u)) >> 16);
}

#define GLOAD_LDS16(g, l)                                           \
  __builtin_amdgcn_global_load_lds(                                 \
      (const __attribute__((address_space(1))) void*)(g),           \
      (__attribute__((address_space(3))) void*)(l), 16, 0, 0)

// ---------------- fused prep ----------------
// One block per 1024-float row. Blocks [0, 8192): support rows -> Sb + smag.
// Blocks [8192, 10240): input rows -> Ib + partials. (finalize kernel removed:
// the GEMM reduces partials itself — kills a serialized 1-block dispatch.)
__global__ __launch_bounds__(256) void prep(
    const float* __restrict__ S, const float* __restrict__ I,
    unsigned short* __restrict__ Sb, unsigned short* __restrict__ Ib,
    float* __restrict__ smag, float* __restrict__ partials) {
  const int t = threadIdx.x;
  const int blk = blockIdx.x;
  const bool isS = blk < M_DIM;
  const int row = isS ? blk : blk - M_DIM;
  const float* src = (isS ? S : I) + (size_t)row * K_DIM;
  unsigned short* dst = (isS ? Sb : Ib) + (size_t)row * K_DIM;

  const float4 v = reinterpret_cast<const float4*>(src)[t];
  ushort4 b;
  b.x = f2bf(v.x); b.y = f2bf(v.y); b.z = f2bf(v.z); b.w = f2bf(v.w);
  reinterpret_cast<ushort4*>(dst)[t] = b;

  float ss = v.x * v.x + v.y * v.y + v.z * v.z + v.w * v.w;
#pragma unroll
  for (int m = 32; m >= 1; m >>= 1) ss += __shfl_xor(ss, m, 64);
  __shared__ float wsum[4];
  if ((t & 63) == 0) wsum[t >> 6] = ss;
  __syncthreads();
  if (t == 0) {
    const float tot = wsum[0] + wsum[1] + wsum[2] + wsum[3];
    if (isS) smag[row] = rsqrtf(fmaxf(tot, 1e-10f));
    else     partials[row] = tot;
  }
}

// ---------------- GEMM ----------------
// C[m,n] = smag[m]*imag * sum_k A[m,k]*B[n,k]  (both row-major NT).
// 128x128 tile, BK=64, XOR-swizzled LDS (0 bank conflicts, verified R2).
// imag is reduced from `partials` in-kernel (pre-K-loop, visibility via the
// first __syncthreads).
__global__ __launch_bounds__(256) void gemm_bt(
    const unsigned short* __restrict__ A,  // [M, K] bf16 (support)
    const unsigned short* __restrict__ B,  // [N, K] bf16 (input)
    const float* __restrict__ smag,        // [M]
    const float* __restrict__ partials,    // [2048] input-row sumsq partials
    float* __restrict__ C) {               // [M, N]
  __shared__ unsigned short lA[BM * BK];   // 16 KB
  __shared__ unsigned short lB[BN * BK];   // 16 KB
  __shared__ float wsum[4];

  const int t = threadIdx.x;
  const int lane = t & 63;
  const int wave = t >> 6;
  const int wr = wave >> 1;  // wave row 0..1
  const int wc = wave & 1;   // wave col 0..1

  // XCD-aware swizzle: dispatch heuristic blk%8 -> XCD. Each XCD owns a
  // contiguous 8-bm stripe; bm fastest within a bn phase -> per-phase
  // working set A 2MB + B 256KB < 4MB XCD L2. (Latency-bound kernel:
  // L2 hit ~200cyc vs ~900cyc shortens the per-barrier vmcnt drain.)
  const int blk = blockIdx.x;
  const int xcd = blk & 7;
  const int slot = blk >> 3;
  const int bn = (slot >> 3) * BN;
  const int bm = (xcd * 8 + (slot & 7)) * BM;

  // Reduce input sum-of-squares (8 loads/thread), result parked in wsum;
  // the K-loop's first __syncthreads makes it visible. Overlaps with staging.
  {
    float p = 0.f;
#pragma unroll
    for (int i = 0; i < 2048 / 256; ++i) p += partials[t + i * 256];
#pragma unroll
    for (int m = 32; m >= 1; m >>= 1) p += __shfl_xor(p, m, 64);
    if ((t & 63) == 0) wsum[t >> 6] = p;
  }

  // Staging: tile = 1024 chunks of 16B, XOR-swizzled: chunk (row,kc) lives at
  // position row*8 + (kc ^ (row&7)).
  const int rsub = lane >> 3;
  const int kcg = (lane & 7) ^ (rsub & 7);
  const unsigned short* gA[4];
  const unsigned short* gB[4];
  unsigned short* dA[4];
  unsigned short* dB[4];
#pragma unroll
  for (int i = 0; i < 4; ++i) {
    const int row = i * 32 + wave * 8 + rsub;
    gA[i] = A + (size_t)(bm + row) * K_DIM + kcg * 8;
    gB[i] = B + (size_t)(bn + row) * K_DIM + kcg * 8;
    dA[i] = lA + (size_t)(i * 256 + wave * 64) * 8;  // wave-uniform base
    dB[i] = lB + (size_t)(i * 256 + wave * 64) * 8;
  }

  // Fragment read bases: A[m = lane&15][k = (lane>>4)*8 + j]
  const int fr = lane & 15;
  const int q = lane >> 4;
  const unsigned short* rA = lA + (wr * 64 + fr) * BK;
  const unsigned short* rB = lB + (wc * 64 + fr) * BK;
  const int sw = fr & 7;  // read-side swizzle term

  float4v acc[4][4];
#pragma unroll
  for (int i = 0; i < 4; ++i)
#pragma unroll
    for (int j = 0; j < 4; ++j) acc[i][j] = (float4v)0.0f;

  for (int kt = 0; kt < K_DIM / BK; ++kt) {
#pragma unroll
    for (int i = 0; i < 4; ++i) GLOAD_LDS16(gA[i], dA[i]);
#pragma unroll
    for (int i = 0; i < 4; ++i) GLOAD_LDS16(gB[i], dB[i]);
#pragma unroll
    for (int i = 0; i < 4; ++i) { gA[i] += BK; gB[i] += BK; }
    __syncthreads();  // drains vmcnt(0): LDS filled before reads

#pragma unroll
    for (int s = 0; s < 2; ++s) {  // two MFMA k-steps per staged slab
      const int pc = ((4 * s + q) ^ sw) * 8;
      short8 af[4], bfr[4];
#pragma unroll
      for (int i = 0; i < 4; ++i)
        af[i] = *reinterpret_cast<const short8*>(rA + i * 16 * BK + pc);
#pragma unroll
      for (int j = 0; j < 4; ++j)
        bfr[j] = *reinterpret_cast<const short8*>(rB + j * 16 * BK + pc);
#pragma unroll
      for (int i = 0; i < 4; ++i)
#pragma unroll
        for (int j = 0; j < 4; ++j)
          acc[i][j] = __builtin_amdgcn_mfma_f32_16x16x32_bf16(af[i], bfr[j], acc[i][j], 0, 0, 0);
    }
    __syncthreads();  // LDS consumed before next iter overwrites
  }

  // Epilogue: C/D layout col = lane&15, row = (lane>>4)*4 + reg
  const float imag = rsqrtf(fmaxf(wsum[0] + wsum[1] + wsum[2] + wsum[3], 1e-10f));
#pragma unroll
  for (int i = 0; i < 4; ++i) {
    const int rbase = bm + wr * 64 + i * 16 + q * 4;
#pragma unroll
    for (int r = 0; r < 4; ++r) {
      const int row = rbase + r;
      const float s = smag[row] * imag;
      float* crow = C + (size_t)row * N_DIM + bn + wc * 64 + fr;
#pragma unroll
      for (int j = 0; j < 4; ++j) crow[j * 16] = acc[i][j][r] * s;
    }
  }
}

// ---------------- launch ----------------
extern "C" void kernel_launch(void* const* d_in, const int* in_sizes, int n_in,
                              void* d_out, int out_size, void* d_ws, size_t ws_size,
                              hipStream_t stream) {
  const float* S = (const float*)d_in[0];  // support_set [8192,1024]
  const float* I = (const float*)d_in[1];  // input_image [2048,1024]
  float* out = (float*)d_out;

  // ws layout: Sb bf16 16MB | Ib bf16 4MB | smag 32KB | partials 8KB
  unsigned char* ws = (unsigned char*)d_ws;
  unsigned short* Sb = (unsigned short*)ws;
  unsigned short* Ib = (unsigned short*)(ws + (size_t)M_DIM * K_DIM * 2);
  float* smag = (float*)(ws + (size_t)M_DIM * K_DIM * 2 + (size_t)N_DIM * K_DIM * 2);
  float* partials = smag + M_DIM;

  hipLaunchKernelGGL(prep, dim3(M_DIM + N_DIM), dim3(256), 0, stream,
                     S, I, Sb, Ib, smag, partials);
  hipLaunchKernelGGL(gemm_bt, dim3((M_DIM / BM) * (N_DIM / BN)), dim3(256), 0, stream,
                     Sb, Ib, smag, partials, out);
}